// Round 10
// baseline (182.230 us; speedup 1.0000x reference)
//
#include <hip/hip_runtime.h>
#include <stdint.h>

// Volterra layer: out = conv3x3(x,w1) + conv3x3(quad,w2) + (b1 + 4*b2)
// quad = sum over 4 shifts of clip(x * circular_shift(x), -1, 1)
// B=8, C=64, H=W=256. Convs are zero-pad SAME; shifts are circular.

typedef short s16x8 __attribute__((ext_vector_type(8)));
typedef float f32x4 __attribute__((ext_vector_type(4)));

__device__ __forceinline__ float clip1(float v) { return fminf(fmaxf(v, -1.f), 1.f); }

__device__ __forceinline__ unsigned short f2bf(float f) {
    union { float f; unsigned u; } v; v.f = f;
    unsigned u = v.u;
    return (unsigned short)((u + 0x7fffu + ((u >> 16) & 1u)) >> 16);
}

__device__ __forceinline__ float bf2f(unsigned short u) {
    union { unsigned v; float f; } t; t.v = ((unsigned)u) << 16; return t.f;
}

// async global->LDS, 16B/lane; global src per-lane, lds dest wave-uniform+lane*16
__device__ __forceinline__ void gload16(const void* g, void* l) {
    __builtin_amdgcn_global_load_lds(
        (const __attribute__((address_space(1))) unsigned int*)g,
        (__attribute__((address_space(3))) unsigned int*)l, 16, 0, 0);
}

// ---------------------------------------------------------------------------
// Kernel 1: weights -> bf16, plain layout Wb[kh][cc][co][kw*32+cci]
// (96 shorts per (co) row). Read directly from L2 by conv8 -- no LDS staging.
// ---------------------------------------------------------------------------
__global__ void prep_w(const float* __restrict__ w1, const float* __restrict__ w2,
                       unsigned short* __restrict__ Wb) {
    int idx = blockIdx.x * 256 + threadIdx.x;   // exactly 73728 threads
    int kk = idx % 96;
    int rest = idx / 96;
    int co = rest & 63; rest >>= 6;
    int cc = rest & 3;
    int kh = rest >> 2;
    int kw = kk >> 5;
    int cci = kk & 31;
    int c2 = cc * 32 + cci;
    const float* src = (c2 < 64) ? w1 : w2;
    int ci = c2 & 63;
    Wb[idx] = f2bf(src[((co * 64 + ci) * 3 + kh) * 3 + kw]);
}

// ---------------------------------------------------------------------------
// Kernel 2: LDS-transposed quad/pack (R2 version -- at HBM floor ~61us).
// U[(b*256+h)*256+w][c2]: c2 0-63 = bf16(x), 64-127 = bf16(quad).
// ---------------------------------------------------------------------------
__global__ __launch_bounds__(512, 1) void prep_u2(const float* __restrict__ x,
                                                  unsigned short* __restrict__ U) {
    __shared__ unsigned short X[3][64][268];
    int bid = blockIdx.x;
    int bh = ((bid & 7) << 8) + (bid >> 3);   // XCD k -> batch image k
    int b = bh >> 8, h = bh & 255;
    int tid = threadIdx.x;

    for (int it = 0; it < 24; ++it) {
        int idx = tid + (it << 9);
        int w4 = idx & 63;
        int c  = (idx >> 6) & 63;
        int r  = idx >> 12;
        int gr = (h + r + 255) & 255;
        const float4 v = *(const float4*)(x + (((size_t)(b * 64 + c)) << 16)
                                            + (gr << 8) + (w4 << 2));
        ushort4 p;
        p.x = f2bf(v.x); p.y = f2bf(v.y); p.z = f2bf(v.z); p.w = f2bf(v.w);
        *(ushort4*)&X[r][c][w4 << 2] = p;
    }
    __syncthreads();

    int c  = tid & 63;
    int wv = tid >> 6;
    int p0 = wv << 5;
    int pm0 = (p0 + 255) & 255;
    float pxc = bf2f(X[1][c][pm0]);
    float pxu = bf2f(X[0][c][pm0]);
    float pxd = bf2f(X[2][c][pm0]);
    size_t base = ((size_t)bh) << 8;
#pragma unroll 4
    for (int i = 0; i < 32; ++i) {
        int p = p0 + i;
        unsigned short xcb = X[1][c][p];
        float xc = bf2f(xcb);
        float xu = bf2f(X[0][c][p]);
        float xd = bf2f(X[2][c][p]);
        float q = clip1(xc * xu) + clip1(xc * pxd) + clip1(xc * pxc) + clip1(xc * pxu);
        size_t po = (base + p) << 7;
        U[po + c]      = xcb;
        U[po + 64 + c] = f2bf(q);
        pxc = xc; pxu = xu; pxd = xd;
    }
}

// ---------------------------------------------------------------------------
// Kernel 3 (v8): small-block high-TLP implicit-GEMM conv.
// Block = 256 thr = 4 waves; 4 output rows x 64 px; wave = one row (64co x 64px,
// acc[4][4]). 3 independent blocks/CU (reg-capped 12 waves) -> stage phases of
// one block overlap compute of the others (no more lockstep serialization).
//  - Input: LDS only. Ib[6][2112] = 25.3 KB, single-buffered, staged via
//    gload16 with inverse-swizzled per-lane GLOBAL src + linear LDS dest:
//    row byte = u*128 + s*16, u = p>>1, s = ((p&1)*4|lq) ^ (u&7)  (b128 bank
//    floor, proven in conv7). Halos p=0 -> bytes [0,64), p=65 -> [4160,4224)
//    lie outside the gload range; ds_write fix-up.
//  - Weights: NO LDS. Per-lane dwordx4 loads straight from L2-hot Wb
//    (147 KB total, shared by all 2048 blocks), batched per kh (12 loads).
// 2 barriers per cc (8 total).
// ---------------------------------------------------------------------------
__global__ __launch_bounds__(256, 3) void conv8(
        const unsigned short* __restrict__ U,
        const unsigned short* __restrict__ Wb,
        const float* __restrict__ b1, const float* __restrict__ b2,
        float* __restrict__ out) {
    __shared__ unsigned short Ib[6][2112];      // 6 x 4224 B = 25344 B

    int bid = blockIdx.x;                          // 2048 blocks
    int logical = ((bid & 7) << 8) + (bid >> 3);   // XCD k -> batch image k
    int b = logical >> 8;
    int rem = logical & 255;
    int h0 = (rem >> 2) << 2;                      // 4 output rows h0..h0+3
    int w0 = (rem & 3) << 6;                       // 64-px column quarter
    int tid = threadIdx.x;
    int wid = tid >> 6;       // wave 0..3 = output row sel  (and stage seg)
    int ln = tid & 63;
    int lr = ln & 15;         // MFMA A-row / C col
    int lq = ln >> 4;         // MFMA k-group / C row-group
    int o = h0 + wid;
    const size_t ubase = ((size_t)b) << 23;

    // per-lane inverse swizzle for staging: dest 16B-unit = 4 + wid*64 + ln
    int D16 = 4 + (wid << 6) + ln;
    int su  = D16 >> 3;                   // pixel-pair unit
    int stv = (D16 & 7) ^ (su & 7);       // logical ((p&1)<<2)|lq
    int pp  = 2 * su + (stv >> 2);        // logical px 1..64
    // global col = w0-1+pp in [w0, w0+63]; channel block = stv&3
    const size_t colbase = (((size_t)(w0 - 1 + pp)) << 7) + (size_t)((stv & 3) * 8);

    f32x4 acc[4][4];
#pragma unroll
    for (int m = 0; m < 4; m++)
#pragma unroll
        for (int n = 0; n < 4; n++) {
            acc[m][n][0] = 0.f; acc[m][n][1] = 0.f; acc[m][n][2] = 0.f; acc[m][n][3] = 0.f;
        }

    auto stage = [&](int ccx) {
        // interior: 6 rows x 1KB seg per wave (seg = wid)
#pragma unroll
        for (int ir = 0; ir < 6; ++ir) {
            int r = h0 - 1 + ir;
            if (r < 0 || r > 255) continue;        // uniform per instr
            const unsigned short* g = U + ubase + (((size_t)r) << 15) + colbase + ccx * 32;
            gload16(g, (char*)&Ib[ir][0] + 64 + (wid << 10));
        }
        // halo px p=0 (bytes q*16) and p=65 (bytes 4160+q*16)
        if (tid < 48) {
            int ir = tid >> 3, r2 = tid & 7;
            int side = r2 >> 2, q = r2 & 3;
            int gcol = side ? (w0 + 64) : (w0 - 1);
            int r = h0 - 1 + ir;
            uint4 v = make_uint4(0u, 0u, 0u, 0u);
            if (gcol >= 0 && gcol <= 255 && r >= 0 && r <= 255)
                v = *(const uint4*)(U + ubase + (((size_t)r) << 15)
                                    + (((size_t)gcol) << 7) + ccx * 32 + q * 8);
            *(uint4*)((char*)&Ib[ir][0] + (side ? 4160 : 0) + q * 16) = v;
        }
        // zero-fill out-of-range rows (zero-pad SAME)
        if (h0 == 0)
            for (int i = tid; i < 264; i += 256)
                *(uint4*)((char*)&Ib[0][0] + i * 16) = make_uint4(0u, 0u, 0u, 0u);
        if (h0 == 252)
            for (int i = tid; i < 264; i += 256)
                *(uint4*)((char*)&Ib[5][0] + i * 16) = make_uint4(0u, 0u, 0u, 0u);
    };

    // ---- prologue --------------------------------------------------------
    stage(0);
    __syncthreads();

    for (int cc = 0; cc < 4; ++cc) {
        // ---- compute: this wave's output row, all 3 kh
#pragma unroll
        for (int kh = 0; kh < 3; ++kh) {
            int ir = wid + kh;                     // input row index in Ib
            const char* ibb = (const char*)&Ib[ir][0];
            // weights for this (kh,cc): 12 frags direct from L2
            const unsigned short* wp = Wb + (size_t)((kh * 4 + cc) * 64) * 96;
            s16x8 af[3][4];
#pragma unroll
            for (int kw = 0; kw < 3; ++kw)
#pragma unroll
                for (int m = 0; m < 4; ++m)
                    af[kw][m] = *(const s16x8*)&wp[(m * 16 + lr) * 96 + kw * 32 + lq * 8];
            __builtin_amdgcn_s_setprio(1);
#pragma unroll
            for (int kw = 0; kw < 3; ++kw) {
                s16x8 bfr[4];
#pragma unroll
                for (int n = 0; n < 4; ++n) {
                    int p = n * 16 + lr + kw;      // 0..65
                    int u = p >> 1;
                    int s = (((p & 1) << 2) | lq) ^ (u & 7);
                    bfr[n] = *(const s16x8*)(ibb + u * 128 + s * 16);
                }
#pragma unroll
                for (int m = 0; m < 4; ++m)
#pragma unroll
                    for (int n = 0; n < 4; ++n)
                        acc[m][n] = __builtin_amdgcn_mfma_f32_16x16x32_bf16(af[kw][m], bfr[n], acc[m][n], 0, 0, 0);
            }
            __builtin_amdgcn_s_setprio(0);
        }
        __syncthreads();                  // Ib free
        if (cc < 3) {
            stage(cc + 1);
            __syncthreads();              // publish
        }
    }

    // ---- epilogue: C/D layout col=lane&15 (pixel), row=(lane>>4)*4+jj (cout)
#pragma unroll
    for (int m = 0; m < 4; m++) {
#pragma unroll
        for (int jj = 0; jj < 4; jj++) {
            int co = m * 16 + lq * 4 + jj;
            float bias = b1[co] + 4.f * b2[co];
#pragma unroll
            for (int n = 0; n < 4; n++) {
                int wpix = w0 + n * 16 + lr;
                out[(((size_t)(b * 64 + co)) << 16) + (o << 8) + wpix] = acc[m][n][jj] + bias;
            }
        }
    }
}

// ---------------------------------------------------------------------------
// Fallback (only if ws too small): direct conv, recomputing quad on the fly.
// ---------------------------------------------------------------------------
__global__ void fallback_conv(const float* __restrict__ x,
                              const float* __restrict__ w1, const float* __restrict__ b1,
                              const float* __restrict__ w2, const float* __restrict__ b2,
                              float* __restrict__ out) {
    size_t idx = (size_t)blockIdx.x * 256 + threadIdx.x;
    int w = idx & 255;
    int h = (int)(idx >> 8) & 255;
    int co = (int)(idx >> 16) & 63;
    int b = (int)(idx >> 22);
    float acc = b1[co] + 4.f * b2[co];
    const float* xb = x + (((size_t)b * 64) << 16);
    for (int ci = 0; ci < 64; ci++) {
        const float* xp = xb + (((size_t)ci) << 16);
        for (int kh = 0; kh < 3; kh++) {
            int hh = h + kh - 1;
            if (hh < 0 || hh > 255) continue;
            for (int kw = 0; kw < 3; kw++) {
                int ww = w + kw - 1;
                if (ww < 0 || ww > 255) continue;
                float xv = xp[(hh << 8) + ww];
                float g1 = w1[((co * 64 + ci) * 3 + kh) * 3 + kw];
                float g2 = w2[((co * 64 + ci) * 3 + kh) * 3 + kw];
                int hm = (hh + 255) & 255, hp = (hh + 1) & 255, wm = (ww + 255) & 255;
                float q = clip1(xv * xp[(hm << 8) + ww]) + clip1(xv * xp[(hp << 8) + wm])
                        + clip1(xv * xp[(hh << 8) + wm]) + clip1(xv * xp[(hm << 8) + wm]);
                acc = fmaf(g1, xv, acc);
                acc = fmaf(g2, q, acc);
            }
        }
    }
    out[idx] = acc;
}

extern "C" void kernel_launch(void* const* d_in, const int* in_sizes, int n_in,
                              void* d_out, int out_size, void* d_ws, size_t ws_size,
                              hipStream_t stream) {
    const float* x  = (const float*)d_in[0];
    const float* w1 = (const float*)d_in[1];
    const float* b1 = (const float*)d_in[2];
    const float* w2 = (const float*)d_in[3];
    const float* b2 = (const float*)d_in[4];
    float* out = (float*)d_out;

    const size_t WB_BYTES = 262144;                       // Wb uses 147456
    const size_t U_BYTES  = (size_t)8 * 256 * 256 * 128 * 2;  // 128 MiB
    if (ws_size >= WB_BYTES + U_BYTES) {
        unsigned short* Wb = (unsigned short*)d_ws;
        unsigned short* U  = (unsigned short*)((char*)d_ws + WB_BYTES);
        prep_w<<<dim3(288), dim3(256), 0, stream>>>(w1, w2, Wb);
        prep_u2<<<dim3(2048), dim3(512), 0, stream>>>(x, U);
        conv8<<<dim3(2048), dim3(256), 0, stream>>>(U, Wb, b1, b2, out);
    } else {
        fallback_conv<<<dim3(131072), dim3(256), 0, stream>>>(x, w1, b1, w2, b2, out);
    }
}

// Round 11
// 163.013 us; speedup vs baseline: 1.1179x; 1.1179x over previous
//
#include <hip/hip_runtime.h>
#include <stdint.h>

// Volterra layer: out = conv3x3(x,w1) + conv3x3(quad,w2) + (b1 + 4*b2)
// quad = sum over 4 shifts of clip(x * circular_shift(x), -1, 1)
// B=8, C=64, H=W=256. Convs are zero-pad SAME; shifts are circular.

typedef short s16x8 __attribute__((ext_vector_type(8)));
typedef float f32x4 __attribute__((ext_vector_type(4)));

__device__ __forceinline__ float clip1(float v) { return fminf(fmaxf(v, -1.f), 1.f); }

__device__ __forceinline__ unsigned short f2bf(float f) {
    union { float f; unsigned u; } v; v.f = f;
    unsigned u = v.u;
    return (unsigned short)((u + 0x7fffu + ((u >> 16) & 1u)) >> 16);
}

__device__ __forceinline__ float bf2f(unsigned short u) {
    union { unsigned v; float f; } t; t.v = ((unsigned)u) << 16; return t.f;
}

// ---------------------------------------------------------------------------
// Kernel 1: weights -> bf16, layout Wb[kh][cc][co][kw*32+cci]
// ---------------------------------------------------------------------------
__global__ void prep_w(const float* __restrict__ w1, const float* __restrict__ w2,
                       unsigned short* __restrict__ Wb) {
    int idx = blockIdx.x * 256 + threadIdx.x;   // exactly 73728 threads
    int kk = idx % 96;
    int rest = idx / 96;
    int co = rest & 63; rest >>= 6;
    int cc = rest & 3;
    int kh = rest >> 2;
    int kw = kk >> 5;
    int cci = kk & 31;
    int c2 = cc * 32 + cci;
    const float* src = (c2 < 64) ? w1 : w2;
    int ci = c2 & 63;
    Wb[idx] = f2bf(src[((co * 64 + ci) * 3 + kh) * 3 + kw]);
}

// ---------------------------------------------------------------------------
// Kernel 2 (v4): quad/pack, CHANNEL-half split for occupancy.
// Block = (b, h, chunk of 32 ch), 512 thr. X[3][32][270] = 51.8 KB ->
// 3 blocks/CU (24 waves vs prep_u2's 8) -- same total traffic (channels are
// disjoint, zero extra halo). Stride 270 shorts = 135 dwords (odd): phase-2
// bank = (135c + p>>1) mod 32, 7c bijective over 32 -> conflict-free.
// U[(b*256+h)*256+w][c2]: chunk k writes x into c2 = k*32+c and quad into
// c2 = 64+k*32+c  (identical layout to before).
// ---------------------------------------------------------------------------
__global__ __launch_bounds__(512, 6) void prep_u4(const float* __restrict__ x,
                                                  unsigned short* __restrict__ U) {
    __shared__ unsigned short X[3][32][270];
    int bid = blockIdx.x;             // 4096 blocks
    int b = bid & 7;                  // image = XCD
    int rest = bid >> 3;              // 0..511
    int h = rest >> 1;
    int chunk = rest & 1;             // which 32-channel half
    int tid = threadIdx.x;

    // phase 1: rows {h-1,h,h+1} (circular), 32 ch, all 256 px.
    // 3*32*64 = 6144 float4 = 12 iters of 512.
    for (int it = 0; it < 12; ++it) {
        int idx = tid + (it << 9);
        int w4 = idx & 63;
        int c  = (idx >> 6) & 31;
        int r  = idx >> 11;
        int gr = (h + r + 255) & 255;
        const float4 v = *(const float4*)(x + (((size_t)(b * 64 + chunk * 32 + c)) << 16)
                                            + (gr << 8) + (w4 << 2));
        ushort4 p;
        p.x = f2bf(v.x); p.y = f2bf(v.y); p.z = f2bf(v.z); p.w = f2bf(v.w);
        *(ushort4*)&X[r][c][w4 << 2] = p;
    }
    __syncthreads();

    // phase 2: lane = (ph, c): c = ln&31, ph = ln>>5; wave owns 32 px
    // (two 16-px runs); register-chained w-1 terms per run.
    int c  = tid & 31;
    int ph = (tid >> 5) & 1;
    int wv = tid >> 6;
    int p0 = (wv << 5) + (ph << 4);
    int pm0 = (p0 + 255) & 255;
    float pxc = bf2f(X[1][c][pm0]);
    float pxu = bf2f(X[0][c][pm0]);
    float pxd = bf2f(X[2][c][pm0]);
    size_t base = ((size_t)(((b << 8) + h))) << 8;
    int cx = chunk * 32 + c;
#pragma unroll 4
    for (int i = 0; i < 16; ++i) {
        int p = p0 + i;
        unsigned short xcb = X[1][c][p];
        float xc = bf2f(xcb);
        float xu = bf2f(X[0][c][p]);
        float xd = bf2f(X[2][c][p]);
        // shifts: (0,1)->x[h-1][w]; (1,-1)->x[h+1][w-1]; (1,0)->x[h][w-1]; (1,1)->x[h-1][w-1]
        float q = clip1(xc * xu) + clip1(xc * pxd) + clip1(xc * pxc) + clip1(xc * pxu);
        size_t po = (base + p) << 7;
        U[po + cx]      = xcb;
        U[po + 64 + cx] = f2bf(q);
        pxc = xc; pxu = xu; pxd = xd;
    }
}

// ---------------------------------------------------------------------------
// Kernel 3 (v5, EXACT R7 measured-best: 100.5us): input-row-stationary
// implicit-GEMM conv, 4 rows x 128 px per block, 512 thr = 8 waves.
// LDS 60.7 KB -> TWO resident blocks/CU; barrier bubbles of one block overlap
// the sibling's compute. Ilds stride 40 / Alds stride 104 (conflict-free per
// 16-lane phase). acc 64 AGPR + 64 arch = 128/wave -> 4 waves/SIMD.
// ---------------------------------------------------------------------------
__global__ __launch_bounds__(512, 4) void conv5(
        const unsigned short* __restrict__ U,
        const unsigned short* __restrict__ Wb,
        const float* __restrict__ b1, const float* __restrict__ b2,
        float* __restrict__ out) {
    __shared__ unsigned short Alds[3][64][104];   // 39936 B
    __shared__ unsigned short Ib[2][130][40];     // 20800 B  (total 60736 B)

    int bid = blockIdx.x;                          // 1024 blocks
    int logical = ((bid & 7) << 7) + (bid >> 3);   // XCD k -> batch image k
    int b = logical >> 7;
    int rem = logical & 127;
    int h0 = (rem >> 1) << 2;                      // 4 output rows h0..h0+3
    int whalf = rem & 1;
    int w0 = whalf << 7;                           // pixel-half base 0 / 128
    int tid = threadIdx.x;
    int wid = tid >> 6;
    int ln = tid & 63;
    int lr = ln & 15;        // MFMA A-row / C col
    int lq = ln >> 4;        // MFMA k-group / C row-group
    int rowsel = wid >> 1;   // which of the 4 output rows
    int pq = wid & 1;        // pixel 64-quarter within the 128-px half
    int o = h0 + rowsel;

    f32x4 acc[4][4];
#pragma unroll
    for (int m = 0; m < 4; m++)
#pragma unroll
        for (int n = 0; n < 4; n++) {
            acc[m][n][0] = 0.f; acc[m][n][1] = 0.f; acc[m][n][2] = 0.f; acc[m][n][3] = 0.f;
        }

    const size_t ubase = ((size_t)b) << 23;

    int cur = 0;
    for (int cc = 0; cc < 4; cc++) {
        // ---- stage weights for all 3 kh of this cc
        for (int i = tid; i < 2304; i += 512) {
            int kh = i / 768;
            int remw = i - kh * 768;
            int co = remw / 12;
            int kk = (remw - co * 12) << 3;
            *(uint4*)&Alds[kh][co][kk] =
                *(const uint4*)&Wb[(((size_t)((kh * 4 + cc) * 64 + co)) * 96) + kk];
        }
        // ---- stage input row j=0 (r = h0-1) into Ib[cur]: 130 px x 4 quads
        {
            int r = h0 - 1;
            if (r >= 0) {
                const unsigned short* usrc = U + ubase + (((size_t)r) << 15) + cc * 32;
                for (int i = tid; i < 520; i += 512) {
                    int p = i >> 2, q = i & 3;
                    int gcol = w0 + p - 1;
                    uint4 v = (gcol < 0 || gcol > 255) ? make_uint4(0u, 0u, 0u, 0u)
                              : *(const uint4*)&usrc[(((size_t)gcol) << 7) + q * 8];
                    *(uint4*)&Ib[cur][p][q * 8] = v;
                }
            }
        }
        __syncthreads();

        for (int j = 0; j < 6; j++) {
            // ---- early-issue loads for next input row (hidden under compute)
            int rn = h0 + j;              // row staged for iteration j+1
            bool have = (j < 5) && (rn <= 255);
            uint4 s0;
            if (have) {
                const unsigned short* usrc = U + ubase + (((size_t)rn) << 15) + cc * 32;
                int p = tid >> 2, q = tid & 3;
                int gcol = w0 + p - 1;
                s0 = (gcol < 0 || gcol > 255) ? make_uint4(0u, 0u, 0u, 0u)
                     : *(const uint4*)&usrc[(((size_t)gcol) << 7) + q * 8];
            }
            // ---- compute stage j: input row r = h0-1+j, this wave's kh = j-rowsel
            int r = h0 - 1 + j;
            int kh = j - rowsel;
            if (kh >= 0 && kh <= 2 && r >= 0 && r <= 255) {
                __builtin_amdgcn_s_setprio(1);
#pragma unroll
                for (int kw = 0; kw < 3; kw++) {
                    s16x8 af[4], bfr[4];
#pragma unroll
                    for (int m = 0; m < 4; m++)
                        af[m] = *(const s16x8*)&Alds[kh][m * 16 + lr][kw * 32 + lq * 8];
#pragma unroll
                    for (int n = 0; n < 4; n++)
                        bfr[n] = *(const s16x8*)&Ib[cur][(pq << 6) + n * 16 + lr + kw][lq * 8];
#pragma unroll
                    for (int m = 0; m < 4; m++)
#pragma unroll
                        for (int n = 0; n < 4; n++)
                            acc[m][n] = __builtin_amdgcn_mfma_f32_16x16x32_bf16(af[m], bfr[n], acc[m][n], 0, 0, 0);
                }
                __builtin_amdgcn_s_setprio(0);
            }
            // ---- write staged regs into the other buffer + tail (p=128,129)
            if (have) {
                { int p = tid >> 2, q = tid & 3; *(uint4*)&Ib[cur ^ 1][p][q * 8] = s0; }
                if (tid < 8) {
                    int i2 = tid + 512;
                    int p = i2 >> 2, q = i2 & 3;
                    int gcol = w0 + p - 1;
                    const unsigned short* usrc = U + ubase + (((size_t)rn) << 15) + cc * 32;
                    uint4 v = (gcol < 0 || gcol > 255) ? make_uint4(0u, 0u, 0u, 0u)
                              : *(const uint4*)&usrc[(((size_t)gcol) << 7) + q * 8];
                    *(uint4*)&Ib[cur ^ 1][p][q * 8] = v;
                }
            }
            __syncthreads();
            if (j < 5) cur ^= 1;
        }
    }

    // epilogue: C/D layout col=lane&15 (pixel), row=(lane>>4)*4+jj (cout)
#pragma unroll
    for (int m = 0; m < 4; m++) {
#pragma unroll
        for (int jj = 0; jj < 4; jj++) {
            int co = m * 16 + lq * 4 + jj;
            float bias = b1[co] + 4.f * b2[co];
#pragma unroll
            for (int n = 0; n < 4; n++) {
                int wpix = w0 + (pq << 6) + n * 16 + lr;
                out[(((size_t)(b * 64 + co)) << 16) + (o << 8) + wpix] = acc[m][n][jj] + bias;
            }
        }
    }
}

// ---------------------------------------------------------------------------
// Fallback (only if ws too small): direct conv, recomputing quad on the fly.
// ---------------------------------------------------------------------------
__global__ void fallback_conv(const float* __restrict__ x,
                              const float* __restrict__ w1, const float* __restrict__ b1,
                              const float* __restrict__ w2, const float* __restrict__ b2,
                              float* __restrict__ out) {
    size_t idx = (size_t)blockIdx.x * 256 + threadIdx.x;
    int w = idx & 255;
    int h = (int)(idx >> 8) & 255;
    int co = (int)(idx >> 16) & 63;
    int b = (int)(idx >> 22);
    float acc = b1[co] + 4.f * b2[co];
    const float* xb = x + (((size_t)b * 64) << 16);
    for (int ci = 0; ci < 64; ci++) {
        const float* xp = xb + (((size_t)ci) << 16);
        for (int kh = 0; kh < 3; kh++) {
            int hh = h + kh - 1;
            if (hh < 0 || hh > 255) continue;
            for (int kw = 0; kw < 3; kw++) {
                int ww = w + kw - 1;
                if (ww < 0 || ww > 255) continue;
                float xv = xp[(hh << 8) + ww];
                float g1 = w1[((co * 64 + ci) * 3 + kh) * 3 + kw];
                float g2 = w2[((co * 64 + ci) * 3 + kh) * 3 + kw];
                int hm = (hh + 255) & 255, hp = (hh + 1) & 255, wm = (ww + 255) & 255;
                float q = clip1(xv * xp[(hm << 8) + ww]) + clip1(xv * xp[(hp << 8) + wm])
                        + clip1(xv * xp[(hh << 8) + wm]) + clip1(xv * xp[(hm << 8) + wm]);
                acc = fmaf(g1, xv, acc);
                acc = fmaf(g2, q, acc);
            }
        }
    }
    out[idx] = acc;
}

extern "C" void kernel_launch(void* const* d_in, const int* in_sizes, int n_in,
                              void* d_out, int out_size, void* d_ws, size_t ws_size,
                              hipStream_t stream) {
    const float* x  = (const float*)d_in[0];
    const float* w1 = (const float*)d_in[1];
    const float* b1 = (const float*)d_in[2];
    const float* w2 = (const float*)d_in[3];
    const float* b2 = (const float*)d_in[4];
    float* out = (float*)d_out;

    const size_t WB_BYTES = 262144;
    const size_t U_BYTES  = (size_t)8 * 256 * 256 * 128 * 2;  // 128 MiB
    if (ws_size >= WB_BYTES + U_BYTES) {
        unsigned short* Wb = (unsigned short*)d_ws;
        unsigned short* U  = (unsigned short*)((char*)d_ws + WB_BYTES);
        prep_w<<<dim3(288), dim3(256), 0, stream>>>(w1, w2, Wb);
        prep_u4<<<dim3(4096), dim3(512), 0, stream>>>(x, U);
        conv5<<<dim3(1024), dim3(512), 0, stream>>>(U, Wb, b1, b2, out);
    } else {
        fallback_conv<<<dim3(131072), dim3(256), 0, stream>>>(x, w1, b1, w2, b2, out);
    }
}